// Round 7
// baseline (321.224 us; speedup 1.0000x reference)
//
#include <hip/hip_runtime.h>
#include <hip/hip_cooperative_groups.h>

namespace cg = cooperative_groups;

#define TLEN 8192
#define DD   4096
#define NF   10
#define NC   12        // 10 a_f coeffs + g + pad
#define NACC 12        // x_sum, pooled, h_f (f=0..9)
#define CCH  128       // chunks
#define ROWS 64        // TLEN / CCH

// ---------- helpers ----------
__device__ __forceinline__ double powi_d(double w, int n) {
    double a = 1.0, p = w;
    while (n) { if (n & 1) a *= p; p *= p; n >>= 1; }
    return a;
}

// =======================================================================
// FUSED cooperative kernel: coef(LDS) + pass + reduce + finalize + gemv + out
// 512 blocks x 256 threads (2 blocks/CU). Phase bodies identical to the
// proven R2 kernels; only orchestration changed.
// =======================================================================
__global__ __launch_bounds__(256) void fused_kernel(
    const float* __restrict__ inp,   const float* __restrict__ hidden,
    const float* __restrict__ w,     const float* __restrict__ pool_w,
    const float* __restrict__ pool_b,
    const float* __restrict__ W1,    const float* __restrict__ b1,
    const float* __restrict__ W2,    const float* __restrict__ b2,
    float* __restrict__ out,
    float* __restrict__ part, float* __restrict__ red,
    float* __restrict__ avg,  float* __restrict__ hid)
{
    cg::grid_group grid = cg::this_grid();
    const int tid = threadIdx.x;
    const int bid = blockIdx.x;

    __shared__ float sc [ROWS * NC];
    __shared__ float scg[ROWS * NF];
    __shared__ float redl[256];

    // ---------------- phase 0+1: per-block coef prologue + streaming pass ----
    {
        const int cgp = bid & 3;          // column group (d-quarter)
        const int ch  = bid >> 2;         // chunk 0..127
        const int t0  = ch * ROWS;

        for (int i = tid; i < ROWS * NF; i += 256) {
            int r = i / NF, f = i - r * NF;
            double wf = (double)w[(size_t)f * DD];   // broadcast along D
            int n = TLEN - 1 - (t0 + r);
            double a = powi_d(wf, n);
            double den = 1.0 - wf;
            sc[r * NC + f] = (float)a;
            scg[i] = (float)((den > 1e-30) ? (double)pool_w[f] * (1.0 - a) / den
                                           : (double)pool_w[f] * (double)n);
        }
        __syncthreads();
        if (tid < ROWS) {
            float g = 0.0f;
#pragma unroll
            for (int f = 0; f < NF; ++f) g += scg[tid * NF + f];
            sc[tid * NC + NF] = g;
        }
        __syncthreads();

        const int d = cgp * 1024 + tid * 4;
        float sx=0,sy=0,sz=0,sw=0;           // x_sum
        float px=0,py=0,pz=0,pw4=0;          // pooled_raw
        float hx[NF], hy[NF], hz[NF], hw[NF];
#pragma unroll
        for (int f = 0; f < NF; ++f) { hx[f]=0; hy[f]=0; hz[f]=0; hw[f]=0; }

        const float* ip = inp + (size_t)t0 * DD + d;
        for (int r = 0; r < ROWS; ++r) {
            float4 x = *(const float4*)ip;
            ip += DD;
            const float* cf = &sc[r * NC];
            sx += x.x; sy += x.y; sz += x.z; sw += x.w;
            float g = cf[NF];
            px  = fmaf(g, x.x, px);  py  = fmaf(g, x.y, py);
            pz  = fmaf(g, x.z, pz);  pw4 = fmaf(g, x.w, pw4);
#pragma unroll
            for (int f = 0; f < NF; ++f) {
                float a = cf[f];
                hx[f] = fmaf(a, x.x, hx[f]); hy[f] = fmaf(a, x.y, hy[f]);
                hz[f] = fmaf(a, x.z, hz[f]); hw[f] = fmaf(a, x.w, hw[f]);
            }
        }

        size_t base = ((size_t)ch * NACC) * DD + d;
        *(float4*)(part + base)      = make_float4(sx, sy, sz, sw);
        *(float4*)(part + base + DD) = make_float4(px, py, pz, pw4);
#pragma unroll
        for (int f = 0; f < NF; ++f)
            *(float4*)(part + base + (size_t)(2 + f) * DD) =
                make_float4(hx[f], hy[f], hz[f], hw[f]);
    }
    grid.sync();

    // ---------------- phase 2: reduce over chunks (192 blocks active) -------
    {
        int idx = bid * 256 + tid;
        if (idx < NACC * DD) {
            float s0=0,s1=0,s2=0,s3=0,s4=0,s5=0,s6=0,s7=0;
            for (int c = 0; c < CCH; c += 8) {
                s0 += part[(size_t)(c+0) * (NACC*DD) + idx];
                s1 += part[(size_t)(c+1) * (NACC*DD) + idx];
                s2 += part[(size_t)(c+2) * (NACC*DD) + idx];
                s3 += part[(size_t)(c+3) * (NACC*DD) + idx];
                s4 += part[(size_t)(c+4) * (NACC*DD) + idx];
                s5 += part[(size_t)(c+5) * (NACC*DD) + idx];
                s6 += part[(size_t)(c+6) * (NACC*DD) + idx];
                s7 += part[(size_t)(c+7) * (NACC*DD) + idx];
            }
            red[idx] = ((s0+s1)+(s2+s3)) + ((s4+s5)+(s6+s7));
        }
    }
    grid.sync();

    // ---------------- phase 3: finalize (blocks 0..3) ------------------------
    {
        if (bid < 4) {
            int i = bid * 256 + tid;   // 0..1023
            int d = i * 4;
            float4 xs = *(const float4*)(red + d);
            float4 pl = *(const float4*)(red + DD + d);
            const float invT = 1.0f / (float)TLEN;
#pragma unroll
            for (int f = 0; f < NF; ++f) {
                double wf = (double)w[(size_t)f * DD];
                double wTd = powi_d(wf, TLEN);
                double den = 1.0 - wf;
                double sTd = (den > 1e-30) ? (1.0 - wTd) / den : (double)TLEN;
                float wT = (float)wTd;
                float pwsT = (float)((double)pool_w[f] * sTd);
                float4 hf = *(const float4*)(red + (size_t)(2 + f) * DD + d);
                float4 h0 = *(const float4*)(hidden + (size_t)f * DD + d);
                hf.x = fmaf(wT, h0.x, hf.x); hf.y = fmaf(wT, h0.y, hf.y);
                hf.z = fmaf(wT, h0.z, hf.z); hf.w = fmaf(wT, h0.w, hf.w);
                pl.x = fmaf(pwsT, h0.x, pl.x); pl.y = fmaf(pwsT, h0.y, pl.y);
                pl.z = fmaf(pwsT, h0.z, pl.z); pl.w = fmaf(pwsT, h0.w, pl.w);
                float* o = out + 10 + (size_t)f * DD + d;  // 40B-misaligned -> scalar
                o[0] = hf.x; o[1] = hf.y; o[2] = hf.z; o[3] = hf.w;
            }
            float pb = pool_b[0];
            avg[d+0] = xs.x * invT; avg[d+1] = xs.y * invT;
            avg[d+2] = xs.z * invT; avg[d+3] = xs.w * invT;
            avg[DD + d + 0] = pl.x * invT + pb; avg[DD + d + 1] = pl.y * invT + pb;
            avg[DD + d + 2] = pl.z * invT + pb; avg[DD + d + 3] = pl.w * invT + pb;
        }
    }
    grid.sync();

    // ---------------- phase 4: GEMV hid = relu(W1 @ avg + b1) ----------------
    {
        int wave = tid >> 6, lane = tid & 63;
#pragma unroll
        for (int rr = 0; rr < 2; ++rr) {
            int row = bid * 8 + wave * 2 + rr;
            const float* wr = W1 + (size_t)row * (2 * DD);
            float acc = 0.0f;
#pragma unroll 8
            for (int j0 = 0; j0 < 32; ++j0) {
                int j = j0 * 256 + lane * 4;
                float4 wv = *(const float4*)(wr + j);
                float4 av = *(const float4*)(avg + j);
                acc = fmaf(wv.x, av.x, acc); acc = fmaf(wv.y, av.y, acc);
                acc = fmaf(wv.z, av.z, acc); acc = fmaf(wv.w, av.w, acc);
            }
            for (int off = 32; off; off >>= 1) acc += __shfl_down(acc, off, 64);
            if (lane == 0) hid[row] = fmaxf(acc + b1[row], 0.0f);
        }
    }
    grid.sync();

    // ---------------- phase 5: out (blocks 0..9) -----------------------------
    {
        if (bid < 10) {
            int o = bid;
            float acc = 0.0f;
            for (int h = tid; h < DD; h += 256)
                acc = fmaf(hid[h], W2[(size_t)o * DD + h], acc);
            redl[tid] = acc;
            __syncthreads();
            for (int s = 128; s; s >>= 1) {
                if (tid < s) redl[tid] += redl[tid + s];
                __syncthreads();
            }
            if (tid == 0) out[o] = redl[0] + b2[o];
        }
    }
}

// =======================================================================
// Fallback path (R2's proven 6-kernel pipeline) if cooperative launch fails
// =======================================================================
__global__ void coef_kernel(const float* __restrict__ w,
                            const float* __restrict__ pool_w,
                            float* __restrict__ coef) {
    int t = blockIdx.x * blockDim.x + threadIdx.x;
    if (t >= TLEN) return;
    int n = TLEN - 1 - t;
    double g = 0.0;
#pragma unroll
    for (int f = 0; f < NF; ++f) {
        double wf = (double)w[(size_t)f * DD];
        double a  = powi_d(wf, n);
        double den = 1.0 - wf;
        double c  = (den > 1e-30) ? (1.0 - a) / den : (double)n;
        g += (double)pool_w[f] * c;
        coef[t * NC + f] = (float)a;
    }
    coef[t * NC + NF]     = (float)g;
    coef[t * NC + NF + 1] = 0.0f;
}

__global__ __launch_bounds__(256) void pass_kernel(const float* __restrict__ inp,
                                                   const float* __restrict__ coef,
                                                   float* __restrict__ part,
                                                   int rows) {
    __shared__ float sc[256 * NC];
    const int t0 = blockIdx.y * rows;
    const int d  = blockIdx.x * 1024 + threadIdx.x * 4;
    float sx=0,sy=0,sz=0,sw=0, px=0,py=0,pz=0,pw4=0;
    float hx[NF], hy[NF], hz[NF], hw[NF];
#pragma unroll
    for (int f = 0; f < NF; ++f) { hx[f]=0; hy[f]=0; hz[f]=0; hw[f]=0; }
    const float* ip = inp + (size_t)t0 * DD + d;
    for (int rbase = 0; rbase < rows; rbase += 256) {
        int rcnt = rows - rbase; if (rcnt > 256) rcnt = 256;
        __syncthreads();
        for (int i = threadIdx.x; i < rcnt * NC; i += 256)
            sc[i] = coef[(size_t)(t0 + rbase) * NC + i];
        __syncthreads();
        for (int r = 0; r < rcnt; ++r) {
            float4 x = *(const float4*)ip; ip += DD;
            const float* cf = &sc[r * NC];
            sx += x.x; sy += x.y; sz += x.z; sw += x.w;
            float g = cf[NF];
            px  = fmaf(g, x.x, px);  py  = fmaf(g, x.y, py);
            pz  = fmaf(g, x.z, pz);  pw4 = fmaf(g, x.w, pw4);
#pragma unroll
            for (int f = 0; f < NF; ++f) {
                float a = cf[f];
                hx[f] = fmaf(a, x.x, hx[f]); hy[f] = fmaf(a, x.y, hy[f]);
                hz[f] = fmaf(a, x.z, hz[f]); hw[f] = fmaf(a, x.w, hw[f]);
            }
        }
    }
    size_t base = ((size_t)blockIdx.y * NACC) * DD + d;
    *(float4*)(part + base)      = make_float4(sx, sy, sz, sw);
    *(float4*)(part + base + DD) = make_float4(px, py, pz, pw4);
#pragma unroll
    for (int f = 0; f < NF; ++f)
        *(float4*)(part + base + (size_t)(2 + f) * DD) =
            make_float4(hx[f], hy[f], hz[f], hw[f]);
}

__global__ void reduce_kernel(const float* __restrict__ part,
                              float* __restrict__ red, int C) {
    int idx = blockIdx.x * blockDim.x + threadIdx.x;
    if (idx >= NACC * DD) return;
    float s = 0.0f;
    for (int c = 0; c < C; ++c)
        s += part[(size_t)c * (NACC*DD) + idx];
    red[idx] = s;
}

__global__ void finalize_kernel(const float* __restrict__ red,
                                const float* __restrict__ w,
                                const float* __restrict__ pool_w,
                                const float* __restrict__ pool_b,
                                const float* __restrict__ hidden,
                                float* __restrict__ out,
                                float* __restrict__ avg) {
    int i = blockIdx.x * blockDim.x + threadIdx.x;
    int d = i * 4;
    float4 xs = *(const float4*)(red + d);
    float4 pl = *(const float4*)(red + DD + d);
    const float invT = 1.0f / (float)TLEN;
#pragma unroll
    for (int f = 0; f < NF; ++f) {
        double wf = (double)w[(size_t)f * DD];
        double wTd = powi_d(wf, TLEN);
        double den = 1.0 - wf;
        double sTd = (den > 1e-30) ? (1.0 - wTd) / den : (double)TLEN;
        float wT = (float)wTd;
        float pwsT = (float)((double)pool_w[f] * sTd);
        float4 hf = *(const float4*)(red + (size_t)(2 + f) * DD + d);
        float4 h0 = *(const float4*)(hidden + (size_t)f * DD + d);
        hf.x = fmaf(wT, h0.x, hf.x); hf.y = fmaf(wT, h0.y, hf.y);
        hf.z = fmaf(wT, h0.z, hf.z); hf.w = fmaf(wT, h0.w, hf.w);
        pl.x = fmaf(pwsT, h0.x, pl.x); pl.y = fmaf(pwsT, h0.y, pl.y);
        pl.z = fmaf(pwsT, h0.z, pl.z); pl.w = fmaf(pwsT, h0.w, pl.w);
        float* o = out + 10 + (size_t)f * DD + d;
        o[0] = hf.x; o[1] = hf.y; o[2] = hf.z; o[3] = hf.w;
    }
    float pb = pool_b[0];
    avg[d+0] = xs.x * invT; avg[d+1] = xs.y * invT;
    avg[d+2] = xs.z * invT; avg[d+3] = xs.w * invT;
    avg[DD + d + 0] = pl.x * invT + pb; avg[DD + d + 1] = pl.y * invT + pb;
    avg[DD + d + 2] = pl.z * invT + pb; avg[DD + d + 3] = pl.w * invT + pb;
}

__global__ __launch_bounds__(256) void gemv_kernel(const float* __restrict__ W,
                                                   const float* __restrict__ b,
                                                   const float* __restrict__ avg,
                                                   float* __restrict__ hid) {
    int row  = blockIdx.x * 4 + (threadIdx.x >> 6);
    int lane = threadIdx.x & 63;
    const float* wr = W + (size_t)row * (2 * DD);
    float acc = 0.0f;
#pragma unroll 8
    for (int j0 = 0; j0 < 32; ++j0) {
        int j = j0 * 256 + lane * 4;
        float4 wv = *(const float4*)(wr + j);
        float4 av = *(const float4*)(avg + j);
        acc = fmaf(wv.x, av.x, acc); acc = fmaf(wv.y, av.y, acc);
        acc = fmaf(wv.z, av.z, acc); acc = fmaf(wv.w, av.w, acc);
    }
    for (int off = 32; off; off >>= 1) acc += __shfl_down(acc, off, 64);
    if (lane == 0) hid[row] = fmaxf(acc + b[row], 0.0f);
}

__global__ void out_kernel(const float* __restrict__ hid,
                           const float* __restrict__ ow,
                           const float* __restrict__ ob,
                           float* __restrict__ out) {
    __shared__ float redl[256];
    int o = blockIdx.x;
    float acc = 0.0f;
    for (int h = threadIdx.x; h < DD; h += 256)
        acc = fmaf(hid[h], ow[(size_t)o * DD + h], acc);
    redl[threadIdx.x] = acc;
    __syncthreads();
    for (int s = 128; s; s >>= 1) {
        if (threadIdx.x < s) redl[threadIdx.x] += redl[threadIdx.x + s];
        __syncthreads();
    }
    if (threadIdx.x == 0) out[o] = redl[0] + ob[o];
}

extern "C" void kernel_launch(void* const* d_in, const int* in_sizes, int n_in,
                              void* d_out, int out_size, void* d_ws, size_t ws_size,
                              hipStream_t stream) {
    const float* inp    = (const float*)d_in[0];
    const float* hidden = (const float*)d_in[1];
    const float* w      = (const float*)d_in[2];
    const float* pw     = (const float*)d_in[3];
    const float* pb     = (const float*)d_in[4];
    const float* i2o_w  = (const float*)d_in[5];
    const float* i2o_b  = (const float*)d_in[6];
    const float* o_w    = (const float*)d_in[7];
    const float* o_b    = (const float*)d_in[8];
    float* out = (float*)d_out;
    float* ws  = (float*)d_ws;

    // workspace layout (floats)
    float* coef = ws;                  // 8192*12 = 98304 (fallback only)
    float* red  = ws + 98304;          // 12*4096 = 49152
    float* avg  = ws + 147456;         // 8192
    float* hid  = ws + 155648;         // 4096
    float* part = ws + 159744;         // 128*12*4096 = 6.29M floats (25 MB)

    void* args[] = {
        (void*)&inp, (void*)&hidden, (void*)&w, (void*)&pw, (void*)&pb,
        (void*)&i2o_w, (void*)&i2o_b, (void*)&o_w, (void*)&o_b,
        (void*)&out, (void*)&part, (void*)&red, (void*)&avg, (void*)&hid
    };
    hipError_t err = hipLaunchCooperativeKernel((const void*)fused_kernel,
                                                dim3(512), dim3(256),
                                                args, 0, stream);
    if (err != hipSuccess) {
        // fallback: R2's proven 6-kernel pipeline
        const int C = CCH, rows = TLEN / CCH;
        coef_kernel<<<TLEN / 256, 256, 0, stream>>>(w, pw, coef);
        pass_kernel<<<dim3(4, C), 256, 0, stream>>>(inp, coef, part, rows);
        reduce_kernel<<<(NACC * DD + 255) / 256, 256, 0, stream>>>(part, red, C);
        finalize_kernel<<<4, 256, 0, stream>>>(red, w, pw, pb, hidden, out, avg);
        gemv_kernel<<<DD / 4, 256, 0, stream>>>(i2o_w, i2o_b, avg, hid);
        out_kernel<<<10, 256, 0, stream>>>(hid, o_w, o_b, out);
    }
}

// Round 8
// 115.351 us; speedup vs baseline: 2.7848x; 2.7848x over previous
//
#include <hip/hip_runtime.h>

#define TLEN 8192
#define DD   4096
#define NF   10
#define NC   12        // 10 a_f coeffs + g + pad
#define NACC 12        // x_sum, pooled, h_f (f=0..9)
#define CCH  128       // chunks
#define ROWS 64        // TLEN / CCH

// ---------- helpers ----------
__device__ __forceinline__ double powi_d(double w, int n) {
    double a = 1.0, p = w;
    while (n) { if (n & 1) a *= p; p *= p; n >>= 1; }
    return a;
}

// ---------- kernel 1: pass with per-block coef prologue ----------
// Grid dim3(4, CCH). Block (bx, ch): columns [bx*1024 .. +1024), rows
// [ch*ROWS .. +ROWS). Prologue computes the 64-row coef table in LDS
// (fp64, spread over threads) -- verified correct in R7's fused phase 0/1.
// Main loop and partial layout byte-identical to the proven R2 pass.
__global__ __launch_bounds__(256) void pass_kernel(const float* __restrict__ inp,
                                                   const float* __restrict__ w,
                                                   const float* __restrict__ pool_w,
                                                   float* __restrict__ part) {
    __shared__ float sc [ROWS * NC];
    __shared__ float scg[ROWS * NF];
    const int ch = blockIdx.y;
    const int t0 = ch * ROWS;

    for (int i = threadIdx.x; i < ROWS * NF; i += 256) {
        int r = i / NF, f = i - r * NF;
        double wf = (double)w[(size_t)f * DD];   // broadcast along D
        int n = TLEN - 1 - (t0 + r);
        double a = powi_d(wf, n);
        double den = 1.0 - wf;
        sc[r * NC + f] = (float)a;
        scg[i] = (float)((den > 1e-30) ? (double)pool_w[f] * (1.0 - a) / den
                                       : (double)pool_w[f] * (double)n);
    }
    __syncthreads();
    if (threadIdx.x < ROWS) {
        float g = 0.0f;
#pragma unroll
        for (int f = 0; f < NF; ++f) g += scg[threadIdx.x * NF + f];
        sc[threadIdx.x * NC + NF] = g;
    }
    __syncthreads();

    const int d = blockIdx.x * 1024 + threadIdx.x * 4;
    float sx=0,sy=0,sz=0,sw=0;           // x_sum
    float px=0,py=0,pz=0,pw4=0;          // pooled_raw
    float hx[NF], hy[NF], hz[NF], hw[NF];
#pragma unroll
    for (int f = 0; f < NF; ++f) { hx[f]=0; hy[f]=0; hz[f]=0; hw[f]=0; }

    const float* ip = inp + (size_t)t0 * DD + d;
    for (int r = 0; r < ROWS; ++r) {
        float4 x = *(const float4*)ip;
        ip += DD;
        const float* cf = &sc[r * NC];
        sx += x.x; sy += x.y; sz += x.z; sw += x.w;
        float g = cf[NF];
        px  = fmaf(g, x.x, px);  py  = fmaf(g, x.y, py);
        pz  = fmaf(g, x.z, pz);  pw4 = fmaf(g, x.w, pw4);
#pragma unroll
        for (int f = 0; f < NF; ++f) {
            float a = cf[f];
            hx[f] = fmaf(a, x.x, hx[f]); hy[f] = fmaf(a, x.y, hy[f]);
            hz[f] = fmaf(a, x.z, hz[f]); hw[f] = fmaf(a, x.w, hw[f]);
        }
    }

    size_t base = ((size_t)ch * NACC) * DD + d;
    *(float4*)(part + base)      = make_float4(sx, sy, sz, sw);
    *(float4*)(part + base + DD) = make_float4(px, py, pz, pw4);
#pragma unroll
    for (int f = 0; f < NF; ++f)
        *(float4*)(part + base + (size_t)(2 + f) * DD) =
            make_float4(hx[f], hy[f], hz[f], hw[f]);
}

// ---------- kernel 2: reduce + finalize fused (per-idx, no cross-block dep) --
// 192 blocks x 256 threads; idx = bid*256+tid in [0, 12*4096). Each block's
// idx range lies in ONE accumulator stream (acc = idx>>12):
//   acc 0      -> avg[d]       = xsum * invT
//   acc 1      -> avg[DD+d]    = (pooled + sum_f pwsT_f*h0[f,d]) * invT + pb
//   acc 2+f    -> out[10+f*DD+d] = h_f + wT_f * h0[f,d]
__global__ __launch_bounds__(256) void redfin_kernel(const float* __restrict__ part,
                                                     const float* __restrict__ w,
                                                     const float* __restrict__ pool_w,
                                                     const float* __restrict__ pool_b,
                                                     const float* __restrict__ hidden,
                                                     float* __restrict__ out,
                                                     float* __restrict__ avg) {
    __shared__ float swT[NF], spwsT[NF];
    if (threadIdx.x < NF) {
        int f = threadIdx.x;
        double wf = (double)w[(size_t)f * DD];
        double wTd = powi_d(wf, TLEN);           // 13 dependent f64 muls (2^13)
        double den = 1.0 - wf;
        double sTd = (den > 1e-30) ? (1.0 - wTd) / den : (double)TLEN;
        swT[f]   = (float)wTd;
        spwsT[f] = (float)((double)pool_w[f] * sTd);
    }
    __syncthreads();

    const int idx = blockIdx.x * 256 + threadIdx.x;
    const int acc = idx >> 12;          // 0..11 (uniform per block: 256 | 4096)
    const int d   = idx & (DD - 1);

    float s0=0,s1=0,s2=0,s3=0,s4=0,s5=0,s6=0,s7=0;
#pragma unroll
    for (int c = 0; c < CCH; c += 8) {
        s0 += part[(size_t)(c+0) * (NACC*DD) + idx];
        s1 += part[(size_t)(c+1) * (NACC*DD) + idx];
        s2 += part[(size_t)(c+2) * (NACC*DD) + idx];
        s3 += part[(size_t)(c+3) * (NACC*DD) + idx];
        s4 += part[(size_t)(c+4) * (NACC*DD) + idx];
        s5 += part[(size_t)(c+5) * (NACC*DD) + idx];
        s6 += part[(size_t)(c+6) * (NACC*DD) + idx];
        s7 += part[(size_t)(c+7) * (NACC*DD) + idx];
    }
    float s = ((s0+s1)+(s2+s3)) + ((s4+s5)+(s6+s7));

    const float invT = 1.0f / (float)TLEN;
    if (acc == 0) {
        avg[d] = s * invT;
    } else if (acc == 1) {
        float corr = 0.0f;
#pragma unroll
        for (int f = 0; f < NF; ++f)
            corr = fmaf(spwsT[f], hidden[(size_t)f * DD + d], corr);
        avg[DD + d] = (s + corr) * invT + pool_b[0];
    } else {
        int f = acc - 2;
        out[10 + (size_t)f * DD + d] = fmaf(swT[f], hidden[(size_t)f * DD + d], s);
    }
}

// ---------- kernel 3: GEMV  hid = relu(i2o_w @ avg + i2o_b)  (R2-identical) --
__global__ __launch_bounds__(256) void gemv_kernel(const float* __restrict__ W,
                                                   const float* __restrict__ b,
                                                   const float* __restrict__ avg,
                                                   float* __restrict__ hid) {
    int row  = blockIdx.x * 4 + (threadIdx.x >> 6);
    int lane = threadIdx.x & 63;
    const float* wr = W + (size_t)row * (2 * DD);
    float acc = 0.0f;
#pragma unroll 8
    for (int j0 = 0; j0 < 32; ++j0) {
        int j = j0 * 256 + lane * 4;
        float4 wv = *(const float4*)(wr + j);
        float4 av = *(const float4*)(avg + j);
        acc = fmaf(wv.x, av.x, acc); acc = fmaf(wv.y, av.y, acc);
        acc = fmaf(wv.z, av.z, acc); acc = fmaf(wv.w, av.w, acc);
    }
    for (int off = 32; off; off >>= 1) acc += __shfl_down(acc, off, 64);
    if (lane == 0) hid[row] = fmaxf(acc + b[row], 0.0f);
}

// ---------- kernel 4: final 10-way dot (R2-identical) ----------
__global__ void out_kernel(const float* __restrict__ hid,
                           const float* __restrict__ ow,
                           const float* __restrict__ ob,
                           float* __restrict__ out) {
    __shared__ float redl[256];
    int o = blockIdx.x;
    float acc = 0.0f;
    for (int h = threadIdx.x; h < DD; h += 256)
        acc = fmaf(hid[h], ow[(size_t)o * DD + h], acc);
    redl[threadIdx.x] = acc;
    __syncthreads();
    for (int s = 128; s; s >>= 1) {
        if (threadIdx.x < s) redl[threadIdx.x] += redl[threadIdx.x + s];
        __syncthreads();
    }
    if (threadIdx.x == 0) out[o] = redl[0] + ob[o];
}

extern "C" void kernel_launch(void* const* d_in, const int* in_sizes, int n_in,
                              void* d_out, int out_size, void* d_ws, size_t ws_size,
                              hipStream_t stream) {
    const float* inp    = (const float*)d_in[0];
    const float* hidden = (const float*)d_in[1];
    const float* w      = (const float*)d_in[2];
    const float* pw     = (const float*)d_in[3];
    const float* pb     = (const float*)d_in[4];
    const float* i2o_w  = (const float*)d_in[5];
    const float* i2o_b  = (const float*)d_in[6];
    const float* o_w    = (const float*)d_in[7];
    const float* o_b    = (const float*)d_in[8];
    float* out = (float*)d_out;
    float* ws  = (float*)d_ws;

    // workspace layout (floats)
    float* avg  = ws;                  // 8192
    float* hid  = ws + 8192;           // 4096
    float* part = ws + 12288;          // 128*12*4096 = 6.29M floats (25 MB)

    // 4 graph nodes (was 6): transitions cost ~10 us each (R5/R2 algebra).
    pass_kernel  <<<dim3(4, CCH), 256, 0, stream>>>(inp, w, pw, part);
    redfin_kernel<<<192, 256, 0, stream>>>(part, w, pw, pb, hidden, out, avg);
    gemv_kernel  <<<DD / 4, 256, 0, stream>>>(i2o_w, i2o_b, avg, hid);
    out_kernel   <<<10, 256, 0, stream>>>(hid, o_w, o_b, out);
}